// Round 1
// baseline (2158.674 us; speedup 1.0000x reference)
//
#include <hip/hip_runtime.h>
#include <hip/hip_bf16.h>
#include <stdint.h>

#define HDIM 4096
#define KW   128          // HDIM/32 packed words per row
#define BROWS 8192
#define NLAYER 3

// ---------------------------------------------------------------------------
// Packing kernels: one thread per source element, wave64 ballot -> 2 words.
// Grids are exact (no tails). Row length 4096 is a multiple of 64, so a wave
// never straddles a row.
// ---------------------------------------------------------------------------
__global__ __launch_bounds__(256) void pack_x_kernel(const float* __restrict__ x,
                                                     uint32_t* __restrict__ ap) {
    int tid = blockIdx.x * 256 + threadIdx.x;
    float v = x[tid];
    // binarize(2x-1): sign bit is exactly (x >= 0.5)
    bool pred = (2.0f * v - 1.0f) >= 0.0f;
    unsigned long long m = __ballot(pred);
    if ((threadIdx.x & 63) == 0) {
        int w = tid >> 5;                 // even, so uint2-aligned
        *(uint2*)(ap + w) = make_uint2((uint32_t)m, (uint32_t)(m >> 32));
    }
}

__global__ __launch_bounds__(256) void pack_sign_kernel(const float* __restrict__ w,
                                                        uint32_t* __restrict__ wp) {
    int tid = blockIdx.x * 256 + threadIdx.x;
    bool pred = w[tid] >= 0.0f;
    unsigned long long m = __ballot(pred);
    if ((threadIdx.x & 63) == 0) {
        int wi = tid >> 5;
        *(uint2*)(wp + wi) = make_uint2((uint32_t)m, (uint32_t)(m >> 32));
    }
}

// rs[l*H+o] = rsqrt(var + 1e-5), computed as correctly-rounded 1/sqrt
__global__ __launch_bounds__(256) void rsqrt_kernel(const float* __restrict__ var,
                                                    float* __restrict__ rs) {
    int tid = blockIdx.x * 256 + threadIdx.x;   // 3*4096 exact
    rs[tid] = 1.0f / sqrtf(var[tid] + 1e-5f);
}

// ---------------------------------------------------------------------------
// Binary GEMM + fused BN + binarize + bit-repack.
// C[b][o] = 4096 - 2*popcount(A[b] ^ W[o]) over 128 words.
// Block: 64x64 outputs, 256 threads (16x16), thread tile 4x4, K-vec uint4.
// ---------------------------------------------------------------------------
#define XP(C, A, B)                                                          \
    C += __popc((A).x ^ (B).x) + __popc((A).y ^ (B).y) +                     \
         __popc((A).z ^ (B).z) + __popc((A).w ^ (B).w)

__device__ __forceinline__ uint32_t pack_row_bits(
    int c0, int c1, int c2, int c3,
    float4 mn, float4 rv, float4 gm, float4 bt, int tx)
{
#pragma clang fp contract(off)
    uint32_t nib = 0;
    float d, t, y;
    d = (float)(4096 - 2 * c0); t = (d - mn.x) * rv.x; y = t * gm.x + bt.x;
    nib |= (y >= 0.0f) ? 1u : 0u;
    d = (float)(4096 - 2 * c1); t = (d - mn.y) * rv.y; y = t * gm.y + bt.y;
    nib |= (y >= 0.0f) ? 2u : 0u;
    d = (float)(4096 - 2 * c2); t = (d - mn.z) * rv.z; y = t * gm.z + bt.z;
    nib |= (y >= 0.0f) ? 4u : 0u;
    d = (float)(4096 - 2 * c3); t = (d - mn.w) * rv.w; y = t * gm.w + bt.w;
    nib |= (y >= 0.0f) ? 8u : 0u;
    uint32_t v = nib << ((tx & 7) * 4);
    v |= __shfl_xor(v, 1);
    v |= __shfl_xor(v, 2);
    v |= __shfl_xor(v, 4);
    return v;   // complete 32-col word in every lane of the 8-lane group
}

__global__ __launch_bounds__(256) void bgemm_kernel(
    const uint32_t* __restrict__ ap,     // [8192][128]
    const uint32_t* __restrict__ wp,     // [4096][128]
    const float* __restrict__ mean, const float* __restrict__ rs,
    const float* __restrict__ gamma, const float* __restrict__ beta,
    uint32_t* __restrict__ apOut)        // [8192][128]
{
    const int tx = threadIdx.x & 15;
    const int ty = threadIdx.x >> 4;
    const int row0 = blockIdx.y * 64 + ty * 4;
    const int col0 = blockIdx.x * 64 + tx * 4;

    const uint4* pa0 = (const uint4*)(ap + (size_t)(row0 + 0) * KW);
    const uint4* pa1 = (const uint4*)(ap + (size_t)(row0 + 1) * KW);
    const uint4* pa2 = (const uint4*)(ap + (size_t)(row0 + 2) * KW);
    const uint4* pa3 = (const uint4*)(ap + (size_t)(row0 + 3) * KW);
    const uint4* pw0 = (const uint4*)(wp + (size_t)(col0 + 0) * KW);
    const uint4* pw1 = (const uint4*)(wp + (size_t)(col0 + 1) * KW);
    const uint4* pw2 = (const uint4*)(wp + (size_t)(col0 + 2) * KW);
    const uint4* pw3 = (const uint4*)(wp + (size_t)(col0 + 3) * KW);

    int c00 = 0, c01 = 0, c02 = 0, c03 = 0;
    int c10 = 0, c11 = 0, c12 = 0, c13 = 0;
    int c20 = 0, c21 = 0, c22 = 0, c23 = 0;
    int c30 = 0, c31 = 0, c32 = 0, c33 = 0;

#pragma unroll 4
    for (int k = 0; k < 32; ++k) {
        uint4 A0 = pa0[k], A1 = pa1[k], A2 = pa2[k], A3 = pa3[k];
        uint4 B0 = pw0[k], B1 = pw1[k], B2 = pw2[k], B3 = pw3[k];
        XP(c00, A0, B0); XP(c01, A0, B1); XP(c02, A0, B2); XP(c03, A0, B3);
        XP(c10, A1, B0); XP(c11, A1, B1); XP(c12, A1, B2); XP(c13, A1, B3);
        XP(c20, A2, B0); XP(c21, A2, B1); XP(c22, A2, B2); XP(c23, A2, B3);
        XP(c30, A3, B0); XP(c31, A3, B1); XP(c32, A3, B2); XP(c33, A3, B3);
    }

    const float4 mn = *(const float4*)(mean + col0);
    const float4 rv = *(const float4*)(rs + col0);
    const float4 gm = *(const float4*)(gamma + col0);
    const float4 bt = *(const float4*)(beta + col0);

    const int wi = blockIdx.x * 2 + (tx >> 3);   // packed word index in row
    uint32_t v;
    v = pack_row_bits(c00, c01, c02, c03, mn, rv, gm, bt, tx);
    if ((tx & 7) == 0) apOut[(size_t)(row0 + 0) * KW + wi] = v;
    v = pack_row_bits(c10, c11, c12, c13, mn, rv, gm, bt, tx);
    if ((tx & 7) == 0) apOut[(size_t)(row0 + 1) * KW + wi] = v;
    v = pack_row_bits(c20, c21, c22, c23, mn, rv, gm, bt, tx);
    if ((tx & 7) == 0) apOut[(size_t)(row0 + 2) * KW + wi] = v;
    v = pack_row_bits(c30, c31, c32, c33, mn, rv, gm, bt, tx);
    if ((tx & 7) == 0) apOut[(size_t)(row0 + 3) * KW + wi] = v;
}

// ---------------------------------------------------------------------------
// Final 8192x10x4096 binary GEMM + TensorNorm (f32 out, tolerance-checked)
// ---------------------------------------------------------------------------
__global__ __launch_bounds__(256) void final_kernel(
    const uint32_t* __restrict__ ap, const uint32_t* __restrict__ wpo,
    const float* __restrict__ tn_m, const float* __restrict__ tn_v,
    const float* __restrict__ tn_w, const float* __restrict__ tn_b,
    float* __restrict__ out)
{
#pragma clang fp contract(off)
    __shared__ uint4 wsh[10][32];
    for (int t = threadIdx.x; t < 320; t += 256)
        ((uint4*)wsh)[t] = ((const uint4*)wpo)[t];
    __syncthreads();

    const int b = blockIdx.x * 256 + threadIdx.x;   // 8192 exact
    const uint4* pa = (const uint4*)(ap + (size_t)b * KW);
    int cnt[10];
#pragma unroll
    for (int o = 0; o < 10; ++o) cnt[o] = 0;

    for (int k = 0; k < 32; ++k) {
        uint4 A = pa[k];
#pragma unroll
        for (int o = 0; o < 10; ++o) {
            uint4 B = wsh[o][k];
            XP(cnt[o], A, B);
        }
    }

    const float m = tn_m[0];
    const float r = 1.0f / sqrtf(tn_v[0] + 1e-4f);
    const float w = tn_w[0];
    const float bb = tn_b[0];
#pragma unroll
    for (int o = 0; o < 10; ++o) {
        float d = (float)(4096 - 2 * cnt[o]);
        float t = (d - m) * r;
        out[b * 10 + o] = t * w + bb;
    }
}

// ---------------------------------------------------------------------------
extern "C" void kernel_launch(void* const* d_in, const int* in_sizes, int n_in,
                              void* d_out, int out_size, void* d_ws, size_t ws_size,
                              hipStream_t stream) {
    const float* x     = (const float*)d_in[0];   // [8192,64,64]
    const float* W     = (const float*)d_in[1];   // [3,4096,4096]
    const float* Wout  = (const float*)d_in[2];   // [10,4096]
    const float* gamma = (const float*)d_in[3];   // [3,4096]
    const float* beta  = (const float*)d_in[4];
    const float* mean  = (const float*)d_in[5];
    const float* var   = (const float*)d_in[6];
    const float* tn_w  = (const float*)d_in[7];
    const float* tn_b  = (const float*)d_in[8];
    const float* tn_m  = (const float*)d_in[9];
    const float* tn_v  = (const float*)d_in[10];
    float* out = (float*)d_out;

    uint8_t* ws = (uint8_t*)d_ws;
    uint32_t* ap0 = (uint32_t*)(ws);                  // 4 MB  [8192][128]
    uint32_t* ap1 = (uint32_t*)(ws + (4u << 20));     // 4 MB
    uint32_t* wp  = (uint32_t*)(ws + (8u << 20));     // 6 MB  [3][4096][128]
    uint32_t* wpo = (uint32_t*)(ws + (14u << 20));    // 5 KB  [10][128]
    float*    rs  = (float*)   (ws + (14u << 20) + 8192); // 48 KB [3][4096]

    // pack input: 8192*4096 = 33,554,432 elems
    pack_x_kernel<<<131072, 256, 0, stream>>>(x, ap0);
    // pack hidden weights: 3*4096*4096 = 50,331,648 elems
    pack_sign_kernel<<<196608, 256, 0, stream>>>(W, wp);
    // pack output weights: 10*4096 = 40,960 elems
    pack_sign_kernel<<<160, 256, 0, stream>>>(Wout, wpo);
    // rsqrt of BN vars: 3*4096 = 12,288 elems
    rsqrt_kernel<<<48, 256, 0, stream>>>(var, rs);

    dim3 grid(64, 128);   // (N/64, M/64)
    bgemm_kernel<<<grid, 256, 0, stream>>>(ap0, wp,               mean,          rs,
                                           gamma,          beta,          ap1);
    bgemm_kernel<<<grid, 256, 0, stream>>>(ap1, wp + 1 * HDIM * KW, mean + HDIM,   rs + HDIM,
                                           gamma + HDIM,   beta + HDIM,   ap0);
    bgemm_kernel<<<grid, 256, 0, stream>>>(ap0, wp + 2 * HDIM * KW, mean + 2*HDIM, rs + 2*HDIM,
                                           gamma + 2*HDIM, beta + 2*HDIM, ap1);

    final_kernel<<<32, 256, 0, stream>>>(ap1, wpo, tn_m, tn_v, tn_w, tn_b, out);
}

// Round 2
// 1882.608 us; speedup vs baseline: 1.1466x; 1.1466x over previous
//
#include <hip/hip_runtime.h>
#include <hip/hip_bf16.h>
#include <stdint.h>

#define KW 128          // 4096 bits / 32 per row

// ---------------------------------------------------------------------------
// Pack f32 -> 1 bit (pred = v >= thresh), writing k-chunk-major layout:
//   dst[l][chunk][row][pos]  == dst[ l*R*128 + (chunk*R + row)*4 + pos ]
// where chunk = kword>>2, pos = kword&3, R = rows per matrix (power of 2).
// Row length is fixed 4096 (128 kwords, 32 chunks). Wave64 ballot produces
// 2 consecutive kwords (even w), which stay inside one uint4 slot -> uint2.
// For x: binarize(2v-1) >= 0  <=>  v >= 0.5 exactly (Sterbenz / sign arg).
// ---------------------------------------------------------------------------
__global__ __launch_bounds__(256) void pack_ksign_kernel(
    const float* __restrict__ src, uint32_t* __restrict__ dst,
    float thresh, int rbits)
{
    int tid = blockIdx.x * 256 + threadIdx.x;
    bool pred = src[tid] >= thresh;
    unsigned long long m = __ballot(pred);
    if ((threadIdx.x & 63) == 0) {
        int w  = (tid & 4095) >> 5;            // kword index, even
        int gr = tid >> 12;                    // global row over all matrices
        int l  = gr >> rbits;
        int r  = gr & ((1 << rbits) - 1);
        size_t base = ((size_t)l << (rbits + 7))
                    + (((size_t)(w >> 2) << rbits) + (size_t)r) * 4
                    + (size_t)(w & 3);
        *(uint2*)(dst + base) = make_uint2((uint32_t)m, (uint32_t)(m >> 32));
    }
}

// Row-major pack for Wout [10][4096] -> [10][128]
__global__ __launch_bounds__(256) void pack_rm_kernel(const float* __restrict__ src,
                                                      uint32_t* __restrict__ dst) {
    int tid = blockIdx.x * 256 + threadIdx.x;
    bool pred = src[tid] >= 0.0f;
    unsigned long long m = __ballot(pred);
    if ((threadIdx.x & 63) == 0)
        *(uint2*)(dst + (tid >> 5)) = make_uint2((uint32_t)m, (uint32_t)(m >> 32));
}

__global__ __launch_bounds__(256) void rsqrt_kernel(const float* __restrict__ var,
                                                    float* __restrict__ rs) {
    int tid = blockIdx.x * 256 + threadIdx.x;   // 3*4096 exact
    rs[tid] = 1.0f / sqrtf(var[tid] + 1e-5f);
}

// ---------------------------------------------------------------------------
// Binary GEMM: C[b][o] = 4096 - 2*popc(A[b]^W[o]); fused BN + binarize + pack.
// A: [32][8192][4] chunk-major, W(layer): [32][4096][4], out: [32][8192][4].
// Block 128x128, 256 threads, 8x8 per thread. LDS double-buffered, one
// barrier/iter. Staging: threads 0..127 stage A rows, 128..255 stage B rows;
// thread t fetches row (t^((t>>3)&7)) and writes LDS slot t (linear writes,
// XOR-swizzled reads -> A reads conflict-free, B reads 2-way (free)).
// ---------------------------------------------------------------------------
__global__ __launch_bounds__(256) void bgemm_kernel(
    const uint32_t* __restrict__ ap,
    const uint32_t* __restrict__ wp,
    const float* __restrict__ mean, const float* __restrict__ rs,
    const float* __restrict__ gamma, const float* __restrict__ beta,
    uint32_t* __restrict__ apOut)
{
    __shared__ uint4 As[2][128];
    __shared__ uint4 Bs[2][128];

    const int t  = threadIdx.x;
    const int tx = t & 15;
    const int ty = t >> 4;
    const int bx = blockIdx.x;      // 0..31  (N/128)
    const int by = blockIdx.y;      // 0..63  (M/128)

    const int  sr   = t & 127;
    const int  qrow = sr ^ ((sr >> 3) & 7);     // row this thread fetches
    const bool isB  = (t >= 128);
    const uint4* gptr = isB
        ? (const uint4*)wp + ((size_t)bx * 128 + qrow)
        : (const uint4*)ap + ((size_t)by * 128 + qrow);
    const size_t gstride = isB ? 4096 : 8192;   // uint4 per k-chunk
    uint4* sdst = isB ? &Bs[0][sr] : &As[0][sr];

    sdst[0] = gptr[0];
    __syncthreads();

    int cnt[8][8];
#pragma unroll
    for (int r = 0; r < 8; ++r)
#pragma unroll
        for (int c = 0; c < 8; ++c) cnt[r][c] = 0;

    const int tyx = ty & 7;
    const int txx = tx & 7;

#pragma unroll 2
    for (int k = 0; k < 32; ++k) {
        const int buf = k & 1;
        uint4 stg;
        if (k < 31) stg = gptr[(size_t)(k + 1) * gstride];

        uint4 a[8], b[8];
#pragma unroll
        for (int r = 0; r < 8; ++r) a[r] = As[buf][ty * 8 + (r ^ tyx)];
#pragma unroll
        for (int c = 0; c < 8; ++c) b[c] = Bs[buf][tx * 8 + (c ^ txx)];

#pragma unroll
        for (int r = 0; r < 8; ++r)
#pragma unroll
            for (int c = 0; c < 8; ++c) {
                cnt[r][c] += __popc(a[r].x ^ b[c].x) + __popc(a[r].y ^ b[c].y)
                           + __popc(a[r].z ^ b[c].z) + __popc(a[r].w ^ b[c].w);
            }

        if (k < 31) sdst[(buf ^ 1) * 128] = stg;
        __syncthreads();
    }

    // Epilogue: BN (exact left-assoc, no FMA contraction) + binarize + pack.
    {
#pragma clang fp contract(off)
        const int col0 = bx * 128 + tx * 8;
        float mnv[8], rvv[8], gmv[8], btv[8];
        *(float4*)&mnv[0] = *(const float4*)(mean + col0);
        *(float4*)&mnv[4] = *(const float4*)(mean + col0 + 4);
        *(float4*)&rvv[0] = *(const float4*)(rs + col0);
        *(float4*)&rvv[4] = *(const float4*)(rs + col0 + 4);
        *(float4*)&gmv[0] = *(const float4*)(gamma + col0);
        *(float4*)&gmv[4] = *(const float4*)(gamma + col0 + 4);
        *(float4*)&btv[0] = *(const float4*)(beta + col0);
        *(float4*)&btv[4] = *(const float4*)(beta + col0 + 4);

        const int row0 = by * 128 + ty * 8;
        const int q    = tx >> 2;            // pos within uint4 slot
        const int sh   = (tx & 3) * 8;
#pragma unroll
        for (int r = 0; r < 8; ++r) {
            uint32_t bits = 0;
#pragma unroll
            for (int c = 0; c < 8; ++c) {
                float d  = (float)(4096 - 2 * cnt[r][c]);
                float tt = (d - mnv[c]) * rvv[c];
                float y  = tt * gmv[c] + btv[c];
                bits |= (y >= 0.0f) ? (1u << c) : 0u;
            }
            uint32_t v = bits << sh;
            v |= __shfl_xor(v, 1);
            v |= __shfl_xor(v, 2);
            if ((tx & 3) == 0) {
                int row = row0 + r;
                apOut[((size_t)bx * 8192 + (size_t)row) * 4 + q] = v;
            }
        }
    }
}

// ---------------------------------------------------------------------------
// Final 8192x10x4096 binary GEMM + TensorNorm. A chunk-major (coalesced).
// ---------------------------------------------------------------------------
__global__ __launch_bounds__(256) void final_kernel(
    const uint32_t* __restrict__ ap, const uint32_t* __restrict__ wpo,
    const float* __restrict__ tn_m, const float* __restrict__ tn_v,
    const float* __restrict__ tn_w, const float* __restrict__ tn_b,
    float* __restrict__ out)
{
#pragma clang fp contract(off)
    __shared__ uint4 wsh[10][32];
    for (int i = threadIdx.x; i < 320; i += 256)
        ((uint4*)wsh)[i] = ((const uint4*)wpo)[i];
    __syncthreads();

    const int b = blockIdx.x * 256 + threadIdx.x;   // 8192 exact
    const uint4* pa = (const uint4*)ap + b;
    int cnt[10];
#pragma unroll
    for (int o = 0; o < 10; ++o) cnt[o] = 0;

    for (int k = 0; k < 32; ++k) {
        uint4 A = pa[(size_t)k * 8192];
#pragma unroll
        for (int o = 0; o < 10; ++o) {
            uint4 B = wsh[o][k];
            cnt[o] += __popc(A.x ^ B.x) + __popc(A.y ^ B.y)
                    + __popc(A.z ^ B.z) + __popc(A.w ^ B.w);
        }
    }

    const float m  = tn_m[0];
    const float r  = 1.0f / sqrtf(tn_v[0] + 1e-4f);
    const float w  = tn_w[0];
    const float bb = tn_b[0];
#pragma unroll
    for (int o = 0; o < 10; ++o) {
        float d = (float)(4096 - 2 * cnt[o]);
        float t = (d - m) * r;
        out[b * 10 + o] = t * w + bb;
    }
}

// ---------------------------------------------------------------------------
extern "C" void kernel_launch(void* const* d_in, const int* in_sizes, int n_in,
                              void* d_out, int out_size, void* d_ws, size_t ws_size,
                              hipStream_t stream) {
    const float* x     = (const float*)d_in[0];
    const float* W     = (const float*)d_in[1];
    const float* Wout  = (const float*)d_in[2];
    const float* gamma = (const float*)d_in[3];
    const float* beta  = (const float*)d_in[4];
    const float* mean  = (const float*)d_in[5];
    const float* var   = (const float*)d_in[6];
    const float* tn_w  = (const float*)d_in[7];
    const float* tn_b  = (const float*)d_in[8];
    const float* tn_m  = (const float*)d_in[9];
    const float* tn_v  = (const float*)d_in[10];
    float* out = (float*)d_out;

    uint8_t* ws = (uint8_t*)d_ws;
    uint32_t* ap0 = (uint32_t*)(ws);                      // 4 MB [32][8192][4]
    uint32_t* ap1 = (uint32_t*)(ws + (4u << 20));         // 4 MB
    uint32_t* wp  = (uint32_t*)(ws + (8u << 20));         // 6 MB [3][32][4096][4]
    uint32_t* wpo = (uint32_t*)(ws + (14u << 20));        // 5 KB [10][128]
    float*    rs  = (float*)   (ws + (14u << 20) + 8192); // 48 KB [3][4096]

    pack_ksign_kernel<<<131072, 256, 0, stream>>>(x, ap0, 0.5f, 13);
    pack_ksign_kernel<<<196608, 256, 0, stream>>>(W, wp, 0.0f, 12);
    pack_rm_kernel<<<160, 256, 0, stream>>>(Wout, wpo);
    rsqrt_kernel<<<48, 256, 0, stream>>>(var, rs);

    dim3 grid(32, 64);   // (N/128, M/128)
    bgemm_kernel<<<grid, 256, 0, stream>>>(ap0, wp,            mean,        rs,
                                           gamma,        beta,        ap1);
    bgemm_kernel<<<grid, 256, 0, stream>>>(ap1, wp + (1u<<19), mean + 4096, rs + 4096,
                                           gamma + 4096, beta + 4096, ap0);
    bgemm_kernel<<<grid, 256, 0, stream>>>(ap0, wp + (2u<<19), mean + 8192, rs + 8192,
                                           gamma + 8192, beta + 8192, ap1);

    final_kernel<<<32, 256, 0, stream>>>(ap1, wpo, tn_m, tn_v, tn_w, tn_b, out);
}